// Round 8
// baseline (182.702 us; speedup 1.0000x reference)
//
#include <hip/hip_runtime.h>
#include <hip/hip_bf16.h>

// Problem: B=4, C=8, N=M=K=1024, DX=1.
// z1[b,c] = W_b (N x M) @ Z_{b,c} (M x K);  z2[b,c] = z1 @ z1^T (symmetric)
// W[b][n][m] = exp(-512 * (x[b][n] - xz[m])^2)
// d_out = [ xz (1024 f32) | z2 (4*8*1024*1024 f32) ]
// ws: W bf16 (8 MB) | Zt bf16 (64 MB, [b][c][k][m]) | z1 bf16 (64 MB, [b][c][n][k])
//
// GEMM1: 256x256 tile, 8 waves, BK=64, 4-phase counted-vmcnt(8),
//        K-loop LDS banks fixed via the r3-proven involution (this round).
// GEMM2: 128x128 SYMM i<=j, 4 waves, BK=32, 3-stage counted-vmcnt(4).
//
// LDS involution (per 1KB region = 16 rows x 64B): logical (row r, 16B chunk c)
// stored at phys slot (r>>1)*8 + ((2c+(r&1)) ^ (r>>1)).  global_load_lds keeps
// a LINEAR dest; the per-lane GLOBAL source is pre-permuted (bijective);
// fragment reads land 2 lanes/bank-quad (free, m136).

typedef __attribute__((ext_vector_type(8))) unsigned short u16x8;
typedef __attribute__((ext_vector_type(8))) __bf16 bf16x8;
typedef __attribute__((ext_vector_type(4))) float f32x4;

typedef __attribute__((address_space(1))) void gvoid;
typedef __attribute__((address_space(3))) void svoid;
#define GLDS(g, s) __builtin_amdgcn_global_load_lds((gvoid*)(g), (svoid*)(s), 16, 0, 0)
#define BAR() asm volatile("s_barrier" ::: "memory")

__device__ __forceinline__ unsigned short f2bf(float f) {
  unsigned int u = __builtin_bit_cast(unsigned int, f);
  u += 0x7fffu + ((u >> 16) & 1u);   // round-to-nearest-even
  return (unsigned short)(u >> 16);
}

__device__ __forceinline__ bf16x8 as_bf16x8(u16x8 v) {
  return __builtin_bit_cast(bf16x8, v);
}

// ---------------- W = exp(-0.5*d^2/exp(2*ls)) as bf16 -----------------------
__global__ void weights_kernel(const float* __restrict__ xz, const float* __restrict__ x,
                               const float* __restrict__ ls, unsigned short* __restrict__ W) {
  int bn = blockIdx.x;
  float xv = x[bn];
  float coef = -0.5f * __expf(-2.0f * ls[0]);
  unsigned short* Wrow = W + (size_t)bn * 1024;
  #pragma unroll
  for (int i = 0; i < 4; ++i) {
    int m = threadIdx.x + i * 256;
    float d = xv - xz[m];
    Wrow[m] = f2bf(__expf(coef * d * d));
  }
}

// ---------------- Zt[b][c][k][m] = bf16(Z[b][c][m][k]) ----------------------
__global__ void transpose_kernel(const float* __restrict__ Z, unsigned short* __restrict__ Zt) {
  __shared__ float tile[64][65];
  int bc = blockIdx.z;
  const float* Zp = Z + ((size_t)bc << 20);
  unsigned short* Ztp = Zt + ((size_t)bc << 20);
  int m0 = blockIdx.x * 64, k0 = blockIdx.y * 64;
  int tx = threadIdx.x & 63, tg = threadIdx.x >> 6;
  #pragma unroll
  for (int i = 0; i < 16; ++i) {
    int ml = tg + i * 4;
    tile[ml][tx] = Zp[(size_t)(m0 + ml) * 1024 + k0 + tx];
  }
  __syncthreads();
  int tx2 = (threadIdx.x & 31) * 2, kg = threadIdx.x >> 5;
  #pragma unroll
  for (int i = 0; i < 8; ++i) {
    int kl = kg + i * 8;
    ushort2 v;
    v.x = f2bf(tile[tx2][kl]);
    v.y = f2bf(tile[tx2 + 1][kl]);
    *(ushort2*)&Ztp[(size_t)(k0 + kl) * 1024 + m0 + tx2] = v;
  }
}

// ---------------- GEMM1: z1 = W @ Zt^T (256x256, 8 waves, 4-phase) ----------
template<bool A_PER_B>
__global__ __launch_bounds__(512, 2)
void gemm_nt8(const unsigned short* __restrict__ A, const unsigned short* __restrict__ B,
              unsigned short* __restrict__ Cbf) {
  extern __shared__ __align__(16) char smem[];   // 128 KB: A 2buf x 32KB @0, B @65536

  const int bid = blockIdx.x;
  const int w = ((bid & 7) << 6) + (bid >> 3);
  const int bc = w >> 4;
  const int t  = w & 15;
  const int bi = t & 3, bj = t >> 2;

  const unsigned short* Ap = A + ((size_t)(A_PER_B ? (bc >> 3) : bc) << 20);
  const unsigned short* Bp = B + ((size_t)bc << 20);
  const int tid = threadIdx.x;
  const int wv = tid >> 6, lane = tid & 63;
  const int wr = wv >> 2, wc = wv & 3;
  const int la = lane & 15, ha = lane >> 4;

  f32x4 acc[8][4] = {};

  // ---- staging source: involuted per-lane global address, linear LDS dest
  const int slog = (lane & 7) ^ (lane >> 3);
  const int rloc = 2 * (lane >> 3) + (slog & 1);     // row within 16-row region
  const int cloc = (slog >> 1) * 8;                  // ushort col within 64B row
  const unsigned short* gA0 = Ap + (size_t)(bi*256 +       wv*16 + rloc) * 1024 + cloc;
  const unsigned short* gA1 = Ap + (size_t)(bi*256 + 128 + wv*16 + rloc) * 1024 + cloc;
  const unsigned short* gB0 = Bp + (size_t)(bj*256 +       wv*16 + rloc) * 1024 + cloc;
  const unsigned short* gB1 = Bp + (size_t)(bj*256 + 128 + wv*16 + rloc) * 1024 + cloc;
  const int ldsw = wv * 1024;

  auto stageA = [&](int d, int kh, int kt) {
    const int ko = kt * 64 + kh * 32;
    char* dst = smem + d * 32768 + kh * 16384 + ldsw;
    GLDS(gA0 + ko, dst); GLDS(gA1 + ko, dst + 8192);
  };
  auto stageB = [&](int d, int kh, int kt) {
    const int ko = kt * 64 + kh * 32;
    char* dst = smem + 65536 + d * 32768 + kh * 16384 + ldsw;
    GLDS(gB0 + ko, dst); GLDS(gB1 + ko, dst + 8192);
  };

  // ---- fragment read bases (involuted; per-thread constant + region*1024)
  const int sphys = ((ha << 1) | (la & 1)) ^ (la >> 1);
  const int abase = wr * 8192 + (la >> 1) * 128 + sphys * 16;
  const int bbase = 65536 + wc * 4096 + (la >> 1) * 128 + sphys * 16;

  u16x8 af[4], bfr[4];
  auto lda = [&](int d, int kh, int ms) {
    const char* p = smem + d * 32768 + kh * 16384 + ms * 4096 + abase;
    af[0] = *(const u16x8*)(p);
    af[1] = *(const u16x8*)(p + 1024);
    af[2] = *(const u16x8*)(p + 2048);
    af[3] = *(const u16x8*)(p + 3072);
  };
  auto ldb = [&](int d, int kh) {
    const char* p = smem + d * 32768 + kh * 16384 + bbase;
    bfr[0] = *(const u16x8*)(p);
    bfr[1] = *(const u16x8*)(p + 1024);
    bfr[2] = *(const u16x8*)(p + 2048);
    bfr[3] = *(const u16x8*)(p + 3072);
  };
  auto mfma16 = [&](int ms) {
    __builtin_amdgcn_s_setprio(1);
    #pragma unroll
    for (int i = 0; i < 4; ++i)
      #pragma unroll
      for (int n = 0; n < 4; ++n)
        acc[ms * 4 + i][n] = __builtin_amdgcn_mfma_f32_16x16x32_bf16(
            as_bf16x8(af[i]), as_bf16x8(bfr[n]), acc[ms * 4 + i][n], 0, 0, 0);
    __builtin_amdgcn_s_setprio(0);
  };

  stageA(0, 0, 0); stageB(0, 0, 0);
  stageA(0, 1, 0); stageB(0, 1, 0);
  stageA(1, 0, 1); stageB(1, 0, 1);
  asm volatile("s_waitcnt vmcnt(8)" ::: "memory");
  BAR();

  for (int tt = 0; tt < 16; ++tt) {
    const int d = tt & 1;
    if (tt < 15) stageA(d ^ 1, 1, tt + 1);
    ldb(d, 0); lda(d, 0, 0);
    BAR(); mfma16(0); BAR();
    if (tt < 15) stageB(d ^ 1, 1, tt + 1);
    lda(d, 0, 1);
    BAR(); mfma16(1);
    if (tt < 15) { asm volatile("s_waitcnt vmcnt(8)" ::: "memory"); }
    else         { asm volatile("s_waitcnt vmcnt(0)" ::: "memory"); }
    BAR();
    if (tt < 14) stageA(d, 0, tt + 2);
    ldb(d, 1); lda(d, 1, 0);
    BAR(); mfma16(0); BAR();
    if (tt < 14) stageB(d, 0, tt + 2);
    lda(d, 1, 1);
    BAR(); mfma16(1);
    if (tt < 14)       { asm volatile("s_waitcnt vmcnt(8)" ::: "memory"); }
    else if (tt == 14) { asm volatile("s_waitcnt vmcnt(4)" ::: "memory"); }
    BAR();
  }

  const size_t cb20 = (size_t)bc << 20;
  unsigned short* sE = (unsigned short*)(smem) + wv * 1152;   // [16][72] per wave
  const int r2 = lane >> 2, ch = lane & 3;
  #pragma unroll
  for (int mb = 0; mb < 8; ++mb) {
    #pragma unroll
    for (int nb = 0; nb < 4; ++nb)
      #pragma unroll
      for (int j = 0; j < 4; ++j)
        sE[(ha * 4 + j) * 72 + nb * 16 + la] = f2bf(acc[mb][nb][j]);
    u16x8 v0 = *(const u16x8*)&sE[r2 * 72 + ch * 16];
    u16x8 v1 = *(const u16x8*)&sE[r2 * 72 + ch * 16 + 8];
    unsigned short* gp = Cbf + cb20 +
        (size_t)(bi * 256 + wr * 128 + mb * 16 + r2) * 1024 + bj * 256 + wc * 64 + ch * 16;
    *(u16x8*)gp = v0;
    *(u16x8*)(gp + 8) = v1;
  }
}

// ---------------- GEMM2: z2 = z1 z1^T (128x128 SYMM, 3-stage, r4-proven) ----
__global__ __launch_bounds__(256, 3)
void gemm2_sym(const unsigned short* __restrict__ A, float* __restrict__ Cf) {
  __shared__ __align__(16) char smem[49152];  // A: 3 x 8KB @0, B: 3 x 8KB @24576

  const int chunk = 144;                      // (36*32)/8
  int w = ((int)blockIdx.x & 7) * chunk + ((int)blockIdx.x >> 3);
  int bc = w / 36;
  int t  = w % 36;
  int bi = 0;
  while (t >= 8 - bi) { t -= 8 - bi; ++bi; }
  int bj = bi + t;                            // i <= j

  const unsigned short* Ap = A + ((size_t)bc << 20);
  const int tid = threadIdx.x;
  const int wave = tid >> 6, lane = tid & 63;
  const int wr = wave >> 1, wc = wave & 1;
  const int la = lane & 15, ha = lane >> 4;
  f32x4 acc[4][4] = {};

  // staging source (pre-swizzled global address; LDS dest stays linear)
  const int slog = (lane & 7) ^ ((lane >> 3) & 7);
  const int rloc = 2 * (lane >> 3) + (slog & 1);
  const int cloc = (slog >> 1) * 8;
  const unsigned short* gA0 = Ap + (size_t)(bi * 128 + (wave * 2)     * 16 + rloc) * 1024 + cloc;
  const unsigned short* gA1 = Ap + (size_t)(bi * 128 + (wave * 2 + 1) * 16 + rloc) * 1024 + cloc;
  const unsigned short* gB0 = Ap + (size_t)(bj * 128 + (wave * 2)     * 16 + rloc) * 1024 + cloc;
  const unsigned short* gB1 = Ap + (size_t)(bj * 128 + (wave * 2 + 1) * 16 + rloc) * 1024 + cloc;

  auto stage = [&](int slot, int kt) {
    char* dA = smem + slot * 8192 + wave * 2048;
    char* dB = smem + 24576 + slot * 8192 + wave * 2048;
    GLDS(gA0 + kt, dA); GLDS(gA1 + kt, dA + 1024);
    GLDS(gB0 + kt, dB); GLDS(gB1 + kt, dB + 1024);
  };

  const int sphys = ((ha << 1) | (la & 1)) ^ (la >> 1);
  const int aoff = wr * 4096 + (la >> 1) * 128 + sphys * 16;
  const int boff = wc * 4096 + (la >> 1) * 128 + sphys * 16;

  auto compute = [&](int slot) {
    const char* rA = smem + slot * 8192;
    const char* rB = smem + 24576 + slot * 8192;
    u16x8 af[4], bfr[4];
    #pragma unroll
    for (int m = 0; m < 4; ++m) af[m]  = *(const u16x8*)(rA + aoff + m * 1024);
    #pragma unroll
    for (int n = 0; n < 4; ++n) bfr[n] = *(const u16x8*)(rB + boff + n * 1024);
    #pragma unroll
    for (int m = 0; m < 4; ++m)
      #pragma unroll
      for (int n = 0; n < 4; ++n)
        acc[m][n] = __builtin_amdgcn_mfma_f32_16x16x32_bf16(
            as_bf16x8(af[m]), as_bf16x8(bfr[n]), acc[m][n], 0, 0, 0);
  };

  stage(0, 0);
  stage(1, 32);
  asm volatile("s_waitcnt vmcnt(4)" ::: "memory");
  __builtin_amdgcn_s_barrier();
  int sl0 = 0, sl1 = 1, sl2 = 2;
  for (int t2 = 0; t2 < 32; ++t2) {
    if (t2 < 30) stage(sl2, (t2 + 2) * 32);
    compute(sl0);
    if (t2 < 30)       asm volatile("s_waitcnt vmcnt(4)" ::: "memory");
    else if (t2 == 30) asm volatile("s_waitcnt vmcnt(0)" ::: "memory");
    if (t2 < 31) __builtin_amdgcn_s_barrier();
    int tmp = sl0; sl0 = sl1; sl1 = sl2; sl2 = tmp;
  }
  __builtin_amdgcn_s_barrier();   // all K-loop LDS reads done before smem reuse

  const size_t cb20 = (size_t)bc << 20;

  // direct coalesced f32 write of the computed (upper) tile
  #pragma unroll
  for (int m = 0; m < 4; ++m) {
    int row0 = bi * 128 + wr * 64 + m * 16 + ha * 4;
    #pragma unroll
    for (int n = 0; n < 4; ++n) {
      int col = bj * 128 + wc * 64 + n * 16 + la;
      #pragma unroll
      for (int j = 0; j < 4; ++j)
        Cf[cb20 + (size_t)(row0 + j) * 1024 + col] = acc[m][n][j];
    }
  }
  if (bi != bj) {
    // mirror: LDS band transpose (32x128 f32 bands), coalesced f32x4 stores
    float (*sT)[129] = (float(*)[129])smem;
    #pragma unroll
    for (int b = 0; b < 4; ++b) {
      if (wr == (b >> 1)) {
        #pragma unroll
        for (int dm = 0; dm < 2; ++dm) {
          int m = (b & 1) * 2 + dm;
          #pragma unroll
          for (int n = 0; n < 4; ++n)
            #pragma unroll
            for (int j = 0; j < 4; ++j)
              sT[dm * 16 + ha * 4 + j][wc * 64 + n * 16 + la] = acc[m][n][j];
        }
      }
      __syncthreads();
      int c  = tid >> 1;
      int r0 = (tid & 1) * 16;
      float* gp = Cf + cb20 + (size_t)(bj * 128 + c) * 1024 + bi * 128 + b * 32 + r0;
      #pragma unroll
      for (int q = 0; q < 4; ++q) {
        f32x4 v;
        #pragma unroll
        for (int k = 0; k < 4; ++k) v[k] = sT[r0 + q * 4 + k][c];
        *(f32x4*)(gp + q * 4) = v;
      }
      __syncthreads();
    }
  }
}

extern "C" void kernel_launch(void* const* d_in, const int* in_sizes, int n_in,
                              void* d_out, int out_size, void* d_ws, size_t ws_size,
                              hipStream_t stream) {
  const float* xz = (const float*)d_in[0];
  const float* z  = (const float*)d_in[1];
  const float* x  = (const float*)d_in[2];
  const float* ls = (const float*)d_in[3];
  float* out = (float*)d_out;

  unsigned short* W  = (unsigned short*)d_ws;          // 8 MB
  unsigned short* Zt = W + ((size_t)4 << 20);          // 64 MB
  unsigned short* z1 = Zt + ((size_t)32 << 20);        // 64 MB

  hipFuncSetAttribute((const void*)gemm_nt8<true>,
                      hipFuncAttributeMaxDynamicSharedMemorySize, 131072);

  hipMemcpyAsync(out, xz, 1024 * sizeof(float), hipMemcpyDeviceToDevice, stream);
  weights_kernel<<<4096, 256, 0, stream>>>(xz, x, ls, W);
  transpose_kernel<<<dim3(16, 16, 32), 256, 0, stream>>>(z, Zt);
  gemm_nt8<true><<<512, 512, 131072, stream>>>(W, Zt, z1);
  gemm2_sym<<<32 * 36, 256, 0, stream>>>(z1, out + 1024);
}

// Round 9
// 172.813 us; speedup vs baseline: 1.0572x; 1.0572x over previous
//
#include <hip/hip_runtime.h>
#include <hip/hip_bf16.h>

// Problem: B=4, C=8, N=M=K=1024, DX=1.
// z1[b,c] = W_b (N x M) @ Z_{b,c} (M x K);  z2[b,c] = z1 @ z1^T (symmetric)
// W[b][n][m] = exp(-512 * (x[b][n] - xz[m])^2)
// d_out = [ xz (1024 f32) | z2 (4*8*1024*1024 f32) ]
// ws: W bf16 (8 MB) | Zt bf16 (64 MB, [b][c][k][m]) | z1 bf16 (64 MB, [b][c][n][k])
//
// GEMM1: 256x256, 8 waves, BK=64. THIS ROUND: register-level fragment
//   pipeline (reads issued one quadrant ahead; MFMA on resident regs;
//   2 barriers/K-tile instead of 8; counted vmcnt(8) publishes each k-half
//   staged a full tile earlier).
// GEMM2: 128x128 SYMM i<=j, 4 waves, BK=32, 3-stage counted-vmcnt(4)
//   (unchanged, r4-proven).
// Note: SQ_LDS_BANK_CONFLICT ~ 8-11 cy per global_load_lds instruction
//   (wave 1KB LDS write serialization) — inherent, not a read-conflict signal.

typedef __attribute__((ext_vector_type(8))) unsigned short u16x8;
typedef __attribute__((ext_vector_type(8))) __bf16 bf16x8;
typedef __attribute__((ext_vector_type(4))) float f32x4;

typedef __attribute__((address_space(1))) void gvoid;
typedef __attribute__((address_space(3))) void svoid;
#define GLDS(g, s) __builtin_amdgcn_global_load_lds((gvoid*)(g), (svoid*)(s), 16, 0, 0)
#define BAR() asm volatile("s_barrier" ::: "memory")

__device__ __forceinline__ unsigned short f2bf(float f) {
  unsigned int u = __builtin_bit_cast(unsigned int, f);
  u += 0x7fffu + ((u >> 16) & 1u);   // round-to-nearest-even
  return (unsigned short)(u >> 16);
}

__device__ __forceinline__ bf16x8 as_bf16x8(u16x8 v) {
  return __builtin_bit_cast(bf16x8, v);
}

// ---------------- W = exp(-0.5*d^2/exp(2*ls)) as bf16 -----------------------
__global__ void weights_kernel(const float* __restrict__ xz, const float* __restrict__ x,
                               const float* __restrict__ ls, unsigned short* __restrict__ W) {
  int bn = blockIdx.x;
  float xv = x[bn];
  float coef = -0.5f * __expf(-2.0f * ls[0]);
  unsigned short* Wrow = W + (size_t)bn * 1024;
  #pragma unroll
  for (int i = 0; i < 4; ++i) {
    int m = threadIdx.x + i * 256;
    float d = xv - xz[m];
    Wrow[m] = f2bf(__expf(coef * d * d));
  }
}

// ---------------- Zt[b][c][k][m] = bf16(Z[b][c][m][k]) ----------------------
__global__ void transpose_kernel(const float* __restrict__ Z, unsigned short* __restrict__ Zt) {
  __shared__ float tile[64][65];
  int bc = blockIdx.z;
  const float* Zp = Z + ((size_t)bc << 20);
  unsigned short* Ztp = Zt + ((size_t)bc << 20);
  int m0 = blockIdx.x * 64, k0 = blockIdx.y * 64;
  int tx = threadIdx.x & 63, tg = threadIdx.x >> 6;
  #pragma unroll
  for (int i = 0; i < 16; ++i) {
    int ml = tg + i * 4;
    tile[ml][tx] = Zp[(size_t)(m0 + ml) * 1024 + k0 + tx];
  }
  __syncthreads();
  int tx2 = (threadIdx.x & 31) * 2, kg = threadIdx.x >> 5;
  #pragma unroll
  for (int i = 0; i < 8; ++i) {
    int kl = kg + i * 8;
    ushort2 v;
    v.x = f2bf(tile[tx2][kl]);
    v.y = f2bf(tile[tx2 + 1][kl]);
    *(ushort2*)&Ztp[(size_t)(k0 + kl) * 1024 + m0 + tx2] = v;
  }
}

// ---------------- GEMM1: z1 = W @ Zt^T (256x256, 8 waves, reg-pipelined) ----
template<bool A_PER_B>
__global__ __launch_bounds__(512, 2)
void gemm_nt8(const unsigned short* __restrict__ A, const unsigned short* __restrict__ B,
              unsigned short* __restrict__ Cbf) {
  extern __shared__ __align__(16) char smem[];   // 128 KB: A 2buf x 32KB @0, B @65536

  const int bid = blockIdx.x;
  const int w = ((bid & 7) << 6) + (bid >> 3);
  const int bc = w >> 4;
  const int t  = w & 15;
  const int bi = t & 3, bj = t >> 2;

  const unsigned short* Ap = A + ((size_t)(A_PER_B ? (bc >> 3) : bc) << 20);
  const unsigned short* Bp = B + ((size_t)bc << 20);
  const int tid = threadIdx.x;
  const int wv = tid >> 6, lane = tid & 63;
  const int wr = wv >> 2, wc = wv & 3;
  const int la = lane & 15, ha = lane >> 4;

  f32x4 acc[8][4] = {};

  // ---- staging source: involuted per-lane global address, linear LDS dest
  const int slog = (lane & 7) ^ (lane >> 3);
  const int rloc = 2 * (lane >> 3) + (slog & 1);     // row within 16-row region
  const int cloc = (slog >> 1) * 8;                  // ushort col within 64B row
  const unsigned short* gA0 = Ap + (size_t)(bi*256 +       wv*16 + rloc) * 1024 + cloc;
  const unsigned short* gA1 = Ap + (size_t)(bi*256 + 128 + wv*16 + rloc) * 1024 + cloc;
  const unsigned short* gB0 = Bp + (size_t)(bj*256 +       wv*16 + rloc) * 1024 + cloc;
  const unsigned short* gB1 = Bp + (size_t)(bj*256 + 128 + wv*16 + rloc) * 1024 + cloc;
  const int ldsw = wv * 1024;

  auto stageA = [&](int d, int kh, int kt) {
    const int ko = kt * 64 + kh * 32;
    char* dst = smem + d * 32768 + kh * 16384 + ldsw;
    GLDS(gA0 + ko, dst); GLDS(gA1 + ko, dst + 8192);
  };
  auto stageB = [&](int d, int kh, int kt) {
    const int ko = kt * 64 + kh * 32;
    char* dst = smem + 65536 + d * 32768 + kh * 16384 + ldsw;
    GLDS(gB0 + ko, dst); GLDS(gB1 + ko, dst + 8192);
  };

  // ---- fragment read bases (involuted; per-thread constant)
  const int sphys = ((ha << 1) | (la & 1)) ^ (la >> 1);
  const int abase = wr * 8192 + (la >> 1) * 128 + sphys * 16;
  const int bbase = 65536 + wc * 4096 + (la >> 1) * 128 + sphys * 16;

  // register fragment double-buffers (statically named -> no scratch)
  u16x8 aX[4], aY[4], b0[4], b1[4];
  auto lda4 = [&](u16x8* dst, int d, int kh, int ms) {
    const char* p = smem + d * 32768 + kh * 16384 + ms * 4096 + abase;
    dst[0] = *(const u16x8*)(p);
    dst[1] = *(const u16x8*)(p + 1024);
    dst[2] = *(const u16x8*)(p + 2048);
    dst[3] = *(const u16x8*)(p + 3072);
  };
  auto ldb4 = [&](u16x8* dst, int d, int kh) {
    const char* p = smem + d * 32768 + kh * 16384 + bbase;
    dst[0] = *(const u16x8*)(p);
    dst[1] = *(const u16x8*)(p + 1024);
    dst[2] = *(const u16x8*)(p + 2048);
    dst[3] = *(const u16x8*)(p + 3072);
  };
  auto mfma16 = [&](const u16x8* Af, const u16x8* Bf, int ms) {
    __builtin_amdgcn_s_setprio(1);
    #pragma unroll
    for (int i = 0; i < 4; ++i)
      #pragma unroll
      for (int n = 0; n < 4; ++n)
        acc[ms * 4 + i][n] = __builtin_amdgcn_mfma_f32_16x16x32_bf16(
            as_bf16x8(Af[i]), as_bf16x8(Bf[n]), acc[ms * 4 + i][n], 0, 0, 0);
    __builtin_amdgcn_s_setprio(0);
  };

  // prologue: tile0 (both halves) + tile1 kh0 in flight; publish tile0 kh0
  stageA(0, 0, 0); stageB(0, 0, 0);
  stageA(0, 1, 0); stageB(0, 1, 0);
  stageA(1, 0, 1); stageB(1, 0, 1);
  asm volatile("s_waitcnt vmcnt(8)" ::: "memory");
  BAR();
  ldb4(b0, 0, 0); lda4(aX, 0, 0, 0);

  // steady state t=0..13: per tile 2 barriers, reads one quadrant ahead.
  // vmcnt(8) ledger: drains exactly the k-half staged one tile earlier.
  for (int tt = 0; tt < 14; ++tt) {
    const int d = tt & 1;
    // q0: compute (kh0, ms0) on resident aX/b0; fetch aY = (kh0, ms1)
    stageA(d ^ 1, 1, tt + 1);
    lda4(aY, d, 0, 1);
    mfma16(aX, b0, 0);
    // q1: publish kh1(t); fetch b1/aX = (kh1, ms0); compute (kh0, ms1)
    stageB(d ^ 1, 1, tt + 1);
    asm volatile("s_waitcnt vmcnt(8)" ::: "memory");
    BAR();
    ldb4(b1, d, 1); lda4(aX, d, 1, 0);
    mfma16(aY, b0, 1);
    // q2: fetch aY = (kh1, ms1); compute (kh1, ms0)
    stageA(d, 0, tt + 2);
    lda4(aY, d, 1, 1);
    mfma16(aX, b1, 0);
    // q3: publish kh0(t+1); cross-tile fetch b0/aX; compute (kh1, ms1)
    stageB(d, 0, tt + 2);
    asm volatile("s_waitcnt vmcnt(8)" ::: "memory");
    BAR();
    ldb4(b0, d ^ 1, 0); lda4(aX, d ^ 1, 0, 0);
    mfma16(aY, b1, 1);
  }
  // tt=14 (d=0): stage only kh1(15); tail vmcnt 8 -> 4
  stageA(1, 1, 15);
  lda4(aY, 0, 0, 1);
  mfma16(aX, b0, 0);
  stageB(1, 1, 15);
  asm volatile("s_waitcnt vmcnt(8)" ::: "memory");
  BAR();
  ldb4(b1, 0, 1); lda4(aX, 0, 1, 0);
  mfma16(aY, b0, 1);
  lda4(aY, 0, 1, 1);
  mfma16(aX, b1, 0);
  asm volatile("s_waitcnt vmcnt(4)" ::: "memory");
  BAR();
  ldb4(b0, 1, 0); lda4(aX, 1, 0, 0);
  mfma16(aY, b1, 1);
  // tt=15 (d=1): no staging; drain
  lda4(aY, 1, 0, 1);
  mfma16(aX, b0, 0);
  asm volatile("s_waitcnt vmcnt(0)" ::: "memory");
  BAR();
  ldb4(b1, 1, 1); lda4(aX, 1, 1, 0);
  mfma16(aY, b0, 1);
  lda4(aY, 1, 1, 1);
  mfma16(aX, b1, 0);
  mfma16(aY, b1, 1);
  BAR();   // all K-loop LDS reads done before smem reuse

  const size_t cb20 = (size_t)bc << 20;
  unsigned short* sE = (unsigned short*)(smem) + wv * 1152;   // [16][72] per wave
  const int r2 = lane >> 2, ch = lane & 3;
  #pragma unroll
  for (int mb = 0; mb < 8; ++mb) {
    #pragma unroll
    for (int nb = 0; nb < 4; ++nb)
      #pragma unroll
      for (int j = 0; j < 4; ++j)
        sE[(ha * 4 + j) * 72 + nb * 16 + la] = f2bf(acc[mb][nb][j]);
    u16x8 v0 = *(const u16x8*)&sE[r2 * 72 + ch * 16];
    u16x8 v1 = *(const u16x8*)&sE[r2 * 72 + ch * 16 + 8];
    unsigned short* gp = Cbf + cb20 +
        (size_t)(bi * 256 + wr * 128 + mb * 16 + r2) * 1024 + bj * 256 + wc * 64 + ch * 16;
    *(u16x8*)gp = v0;
    *(u16x8*)(gp + 8) = v1;
  }
}

// ---------------- GEMM2: z2 = z1 z1^T (128x128 SYMM, 3-stage, r4-proven) ----
__global__ __launch_bounds__(256, 3)
void gemm2_sym(const unsigned short* __restrict__ A, float* __restrict__ Cf) {
  __shared__ __align__(16) char smem[49152];  // A: 3 x 8KB @0, B: 3 x 8KB @24576

  const int chunk = 144;                      // (36*32)/8
  int w = ((int)blockIdx.x & 7) * chunk + ((int)blockIdx.x >> 3);
  int bc = w / 36;
  int t  = w % 36;
  int bi = 0;
  while (t >= 8 - bi) { t -= 8 - bi; ++bi; }
  int bj = bi + t;                            // i <= j

  const unsigned short* Ap = A + ((size_t)bc << 20);
  const int tid = threadIdx.x;
  const int wave = tid >> 6, lane = tid & 63;
  const int wr = wave >> 1, wc = wave & 1;
  const int la = lane & 15, ha = lane >> 4;
  f32x4 acc[4][4] = {};

  // staging source (pre-swizzled global address; LDS dest stays linear)
  const int slog = (lane & 7) ^ ((lane >> 3) & 7);
  const int rloc = 2 * (lane >> 3) + (slog & 1);
  const int cloc = (slog >> 1) * 8;
  const unsigned short* gA0 = Ap + (size_t)(bi * 128 + (wave * 2)     * 16 + rloc) * 1024 + cloc;
  const unsigned short* gA1 = Ap + (size_t)(bi * 128 + (wave * 2 + 1) * 16 + rloc) * 1024 + cloc;
  const unsigned short* gB0 = Ap + (size_t)(bj * 128 + (wave * 2)     * 16 + rloc) * 1024 + cloc;
  const unsigned short* gB1 = Ap + (size_t)(bj * 128 + (wave * 2 + 1) * 16 + rloc) * 1024 + cloc;

  auto stage = [&](int slot, int kt) {
    char* dA = smem + slot * 8192 + wave * 2048;
    char* dB = smem + 24576 + slot * 8192 + wave * 2048;
    GLDS(gA0 + kt, dA); GLDS(gA1 + kt, dA + 1024);
    GLDS(gB0 + kt, dB); GLDS(gB1 + kt, dB + 1024);
  };

  const int sphys = ((ha << 1) | (la & 1)) ^ (la >> 1);
  const int aoff = wr * 4096 + (la >> 1) * 128 + sphys * 16;
  const int boff = wc * 4096 + (la >> 1) * 128 + sphys * 16;

  auto compute = [&](int slot) {
    const char* rA = smem + slot * 8192;
    const char* rB = smem + 24576 + slot * 8192;
    u16x8 af[4], bfr[4];
    #pragma unroll
    for (int m = 0; m < 4; ++m) af[m]  = *(const u16x8*)(rA + aoff + m * 1024);
    #pragma unroll
    for (int n = 0; n < 4; ++n) bfr[n] = *(const u16x8*)(rB + boff + n * 1024);
    #pragma unroll
    for (int m = 0; m < 4; ++m)
      #pragma unroll
      for (int n = 0; n < 4; ++n)
        acc[m][n] = __builtin_amdgcn_mfma_f32_16x16x32_bf16(
            as_bf16x8(af[m]), as_bf16x8(bfr[n]), acc[m][n], 0, 0, 0);
  };

  stage(0, 0);
  stage(1, 32);
  asm volatile("s_waitcnt vmcnt(4)" ::: "memory");
  __builtin_amdgcn_s_barrier();
  int sl0 = 0, sl1 = 1, sl2 = 2;
  for (int t2 = 0; t2 < 32; ++t2) {
    if (t2 < 30) stage(sl2, (t2 + 2) * 32);
    compute(sl0);
    if (t2 < 30)       asm volatile("s_waitcnt vmcnt(4)" ::: "memory");
    else if (t2 == 30) asm volatile("s_waitcnt vmcnt(0)" ::: "memory");
    if (t2 < 31) __builtin_amdgcn_s_barrier();
    int tmp = sl0; sl0 = sl1; sl1 = sl2; sl2 = tmp;
  }
  __builtin_amdgcn_s_barrier();   // all K-loop LDS reads done before smem reuse

  const size_t cb20 = (size_t)bc << 20;

  // direct coalesced f32 write of the computed (upper) tile
  #pragma unroll
  for (int m = 0; m < 4; ++m) {
    int row0 = bi * 128 + wr * 64 + m * 16 + ha * 4;
    #pragma unroll
    for (int n = 0; n < 4; ++n) {
      int col = bj * 128 + wc * 64 + n * 16 + la;
      #pragma unroll
      for (int j = 0; j < 4; ++j)
        Cf[cb20 + (size_t)(row0 + j) * 1024 + col] = acc[m][n][j];
    }
  }
  if (bi != bj) {
    // mirror: LDS band transpose (32x128 f32 bands), coalesced f32x4 stores
    float (*sT)[129] = (float(*)[129])smem;
    #pragma unroll
    for (int b = 0; b < 4; ++b) {
      if (wr == (b >> 1)) {
        #pragma unroll
        for (int dm = 0; dm < 2; ++dm) {
          int m = (b & 1) * 2 + dm;
          #pragma unroll
          for (int n = 0; n < 4; ++n)
            #pragma unroll
            for (int j = 0; j < 4; ++j)
              sT[dm * 16 + ha * 4 + j][wc * 64 + n * 16 + la] = acc[m][n][j];
        }
      }
      __syncthreads();
      int c  = tid >> 1;
      int r0 = (tid & 1) * 16;
      float* gp = Cf + cb20 + (size_t)(bj * 128 + c) * 1024 + bi * 128 + b * 32 + r0;
      #pragma unroll
      for (int q = 0; q < 4; ++q) {
        f32x4 v;
        #pragma unroll
        for (int k = 0; k < 4; ++k) v[k] = sT[r0 + q * 4 + k][c];
        *(f32x4*)(gp + q * 4) = v;
      }
      __syncthreads();
    }
  }
}

extern "C" void kernel_launch(void* const* d_in, const int* in_sizes, int n_in,
                              void* d_out, int out_size, void* d_ws, size_t ws_size,
                              hipStream_t stream) {
  const float* xz = (const float*)d_in[0];
  const float* z  = (const float*)d_in[1];
  const float* x  = (const float*)d_in[2];
  const float* ls = (const float*)d_in[3];
  float* out = (float*)d_out;

  unsigned short* W  = (unsigned short*)d_ws;          // 8 MB
  unsigned short* Zt = W + ((size_t)4 << 20);          // 64 MB
  unsigned short* z1 = Zt + ((size_t)32 << 20);        // 64 MB

  hipFuncSetAttribute((const void*)gemm_nt8<true>,
                      hipFuncAttributeMaxDynamicSharedMemorySize, 131072);

  hipMemcpyAsync(out, xz, 1024 * sizeof(float), hipMemcpyDeviceToDevice, stream);
  weights_kernel<<<4096, 256, 0, stream>>>(xz, x, ls, W);
  transpose_kernel<<<dim3(16, 16, 32), 256, 0, stream>>>(z, Zt);
  gemm_nt8<true><<<512, 512, 131072, stream>>>(W, Zt, z1);
  gemm2_sym<<<32 * 36, 256, 0, stream>>>(z1, out + 1024);
}